// Round 2
// baseline (197.704 us; speedup 1.0000x reference)
//
#include <hip/hip_runtime.h>

#define NB   32
#define NC   3
#define NH   512
#define NW   512
#define KS   25
#define HALF 12
#define TILE 64
#define HALO 88    // TILE + 2*HALF
#define NS   60

__device__ __forceinline__ float clip01(float v) { return fminf(fmaxf(v, 0.f), 1.f); }

struct PParams {
  int f1, f2, f3, f4;
  float intensity, cx, cy, rxi, ryi;
  float oy0, oy1, ox0, ox1;
  float log1ma, nrain;
  float thr_lo, thr_hi;
};

// ---- rain column lists: each streak covers exactly 2 columns ----
__global__ void rain_cols_kernel(const float* __restrict__ rain_u,
                                 const float* __restrict__ rain_n_u,
                                 int* __restrict__ nlist,
                                 unsigned* __restrict__ packed)
{
  int t = blockIdx.x * 256 + threadIdx.x;      // t in [0, 32*512)
  if (t >= NB * NW) return;
  int b = t >> 9, wcol = t & 511;
  float n = floorf(20.f + 41.f * rain_n_u[b]);
  float wf = (float)wcol;
  int cnt = 0;
  for (int s = 0; s < NS; ++s) {
    if ((float)s < n) {
      float xc = floorf(rain_u[(b * NS + s) * 3 + 0] * 512.f);
      if (wf >= xc - 1.f && wf <= xc) {
        float y0 = floorf(rain_u[(b * NS + s) * 3 + 1] * 256.f);
        float y1 = 256.f + floorf(rain_u[(b * NS + s) * 3 + 2] * 256.f);
        packed[t * NS + cnt] = (((unsigned)y0) << 16) | (unsigned)y1;
        ++cnt;
      }
    }
  }
  nlist[t] = cnt;
}

// ---- pointwise chain applied to an 8-row column strip ----
template<bool USE_LISTS>
__device__ __forceinline__ void chain_and_store(
    float acc[8], const PParams& P, int b, int gx, int gy0,
    const float* __restrict__ noise_plane, const float* __restrict__ rain_u,
    const int* __restrict__ nlist, const unsigned* __restrict__ packed,
    float* __restrict__ out_plane)
{
  const float fx = (float)gx;

  // 2. glare
  if (P.f1) {
    float dx = (fx - P.cx) * P.rxi;
    float dx2 = dx * dx;
    #pragma unroll
    for (int k = 0; k < 8; ++k) {
      float dy = ((float)(gy0 + k) - P.cy) * P.ryi;
      float g = __expf(-(dx2 + dy * dy));
      acc[k] = clip01(acc[k] + P.intensity * g);
    }
  }
  // 3. occlusion
  if (P.f2 && fx >= P.ox0 && fx < P.ox1) {
    #pragma unroll
    for (int k = 0; k < 8; ++k) {
      float fy = (float)(gy0 + k);
      if (fy >= P.oy0 && fy < P.oy1) acc[k] = 0.f;
    }
  }
  // 4. rain
  if (P.f3) {
    float cnt[8];
    #pragma unroll
    for (int k = 0; k < 8; ++k) cnt[k] = 0.f;
    if (USE_LISTS) {
      int base = b * NW + gx;
      int c = nlist[base];
      for (int j = 0; j < c; ++j) {
        unsigned p = packed[base * NS + j];
        float y0 = (float)(p >> 16), y1 = (float)(p & 0xffffu);
        #pragma unroll
        for (int k = 0; k < 8; ++k) {
          float fy = (float)(gy0 + k);
          cnt[k] += (fy >= y0 && fy < y1) ? 1.f : 0.f;
        }
      }
    } else {
      for (int s = 0; s < NS; ++s) {
        if ((float)s < P.nrain) {
          float xc = floorf(rain_u[(b * NS + s) * 3 + 0] * 512.f);
          if (fx >= xc - 1.f && fx <= xc) {
            float y0 = floorf(rain_u[(b * NS + s) * 3 + 1] * 256.f);
            float y1 = 256.f + floorf(rain_u[(b * NS + s) * 3 + 2] * 256.f);
            #pragma unroll
            for (int k = 0; k < 8; ++k) {
              float fy = (float)(gy0 + k);
              cnt[k] += (fy >= y0 && fy < y1) ? 1.f : 0.f;
            }
          }
        }
      }
    }
    #pragma unroll
    for (int k = 0; k < 8; ++k) {
      if (cnt[k] != 0.f) {
        float d = exp2f(cnt[k] * P.log1ma);
        acc[k] = clip01(acc[k] * d + (1.f - d));
      }
    }
  }
  // 5. salt & pepper (read noise only when gated on)
  if (P.f4) {
    const float* np = noise_plane + (size_t)gy0 * NW + gx;
    #pragma unroll
    for (int k = 0; k < 8; ++k) {
      float nv = np[(size_t)k * NW];
      acc[k] = (nv < P.thr_lo) ? 0.f : ((nv > P.thr_hi) ? 1.f : acc[k]);
    }
  }
  float* op = out_plane + (size_t)gy0 * NW + gx;
  #pragma unroll
  for (int k = 0; k < 8; ++k) op[(size_t)k * NW] = acc[k];
}

template<bool USE_LISTS>
__global__ __launch_bounds__(256, 6)
void fused_kernel(const float* __restrict__ x, const float* __restrict__ sigma_u,
                  const float* __restrict__ glare_u, const float* __restrict__ occ_u,
                  const float* __restrict__ rain_u, const float* __restrict__ rain_n_u,
                  const float* __restrict__ rain_alpha_u, const float* __restrict__ noise_u,
                  const float* __restrict__ noise_amt_u, const int* __restrict__ flags,
                  const int* __restrict__ nlist, const unsigned* __restrict__ packed,
                  float* __restrict__ out)
{
  const int b = blockIdx.z, ch = blockIdx.y;
  const int ty0 = (blockIdx.x >> 3) * TILE, tx0 = (blockIdx.x & 7) * TILE;
  const int tid = threadIdx.x;

  const int f0 = flags[b * 5 + 0] > 0;
  PParams P;
  P.f1 = flags[b * 5 + 1] > 0;
  P.f2 = flags[b * 5 + 2] > 0;
  P.f3 = flags[b * 5 + 3] > 0;
  P.f4 = flags[b * 5 + 4] > 0;
  {
    float g0 = glare_u[b * 5 + 0], g1 = glare_u[b * 5 + 1], g2 = glare_u[b * 5 + 2],
          g3 = glare_u[b * 5 + 3], g4 = glare_u[b * 5 + 4];
    P.intensity = 0.4f + 0.5f * g0;
    P.rxi = 1.f / ((0.1f + 0.25f * g1) * 256.f);   // W/2
    P.ryi = 1.f / ((0.1f + 0.25f * g2) * 256.f);   // H/2
    P.cx = (0.2f + 0.6f * g3) * 512.f;
    P.cy = (0.2f + 0.6f * g4) * 512.f;
    float o0 = occ_u[b * 4 + 0], o1 = occ_u[b * 4 + 1],
          o2 = occ_u[b * 4 + 2], o3 = occ_u[b * 4 + 3];
    float ph = floorf(512.f * (0.1f + 0.3f * o0));
    float pw = floorf(512.f * (0.1f + 0.3f * o1));
    P.oy0 = floorf(o2 * (512.f - ph)); P.oy1 = P.oy0 + ph;
    P.ox0 = floorf(o3 * (512.f - pw)); P.ox1 = P.ox0 + pw;
    P.log1ma = log2f(1.f - (0.15f + 0.35f * rain_alpha_u[b]));
    P.nrain = floorf(20.f + 41.f * rain_n_u[b]);
    float half_amt = 0.5f * (0.01f + 0.07f * noise_amt_u[b]);
    P.thr_lo = half_amt; P.thr_hi = 1.f - half_amt;
  }

  const size_t plane = ((size_t)(b * NC + ch)) * (size_t)(NH * NW);
  const float* xp = x + plane;
  const float* np = noise_u + plane;
  float* op = out + plane;

  // Only the H-blurred tile is staged in LDS: 88 rows x 64 cols = 22.5 KB
  // -> 7 blocks/CU (vs 2 with the old 53.75 KB raw+hb pair).
  __shared__ __align__(16) float s_hb[HALO * TILE];

  if (f0) {
    // ---- blur weights in registers (25 expf per thread, no LDS, no sync) ----
    float sig = 1.f + 3.f * sigma_u[b];
    float ninv2s2 = -1.f / (2.f * sig * sig);
    float wr[KS]; float s = 0.f;
    #pragma unroll
    for (int t = 0; t < KS; ++t) {
      float d = (float)t - 12.f;
      wr[t] = expf(d * d * ninv2s2);
      s += wr[t];
    }
    float inv = 1.f / s;
    #pragma unroll
    for (int t = 0; t < KS; ++t) wr[t] *= inv;

    // ---- stage 1: horizontal blur straight from global (L1/L2-cached rows),
    //      4 outputs/thread, aligned float4 loads on the interior fast path ----
    for (int i = tid; i < HALO * 16; i += 256) {
      int r = i >> 4, q = i & 15;
      int gy = ty0 + r - HALF;
      float a0 = 0.f, a1 = 0.f, a2 = 0.f, a3 = 0.f;
      if ((unsigned)gy < (unsigned)NH) {
        const float* rowp = xp + (size_t)gy * NW;
        int gx0 = tx0 + q * 4;                    // first of 4 output columns
        float win[28];
        if (gx0 - HALF >= 0 && gx0 + 15 < NW) {   // interior: 7 aligned float4
          #pragma unroll
          for (int j = 0; j < 7; ++j) {
            float4 v = *reinterpret_cast<const float4*>(rowp + gx0 - HALF + 4 * j);
            win[4 * j + 0] = v.x; win[4 * j + 1] = v.y;
            win[4 * j + 2] = v.z; win[4 * j + 3] = v.w;
          }
        } else {                                  // x-edge: guarded scalar loads
          #pragma unroll
          for (int j = 0; j < 28; ++j) {
            int gx = gx0 - HALF + j;
            win[j] = ((unsigned)gx < (unsigned)NW) ? rowp[gx] : 0.f;
          }
        }
        #pragma unroll
        for (int t = 0; t < KS; ++t) {
          float wt = wr[t];
          a0 = fmaf(wt, win[t + 0], a0);
          a1 = fmaf(wt, win[t + 1], a1);
          a2 = fmaf(wt, win[t + 2], a2);
          a3 = fmaf(wt, win[t + 3], a3);
        }
      }
      *reinterpret_cast<float4*>(&s_hb[r * TILE + (i & 15) * 4]) =
          make_float4(a0, a1, a2, a3);
    }
    __syncthreads();

    // ---- stage 2: vertical blur on 8-row strips + fused pointwise chain ----
    for (int i = tid; i < 512; i += 256) {
      int xq = i & 63, sy = i >> 6;
      int gx = tx0 + xq, gy0 = ty0 + sy * 8;
      float wincol[32];
      #pragma unroll
      for (int j = 0; j < 32; ++j) wincol[j] = s_hb[(sy * 8 + j) * TILE + xq];
      float acc[8];
      #pragma unroll
      for (int k = 0; k < 8; ++k) {
        float a = 0.f;
        #pragma unroll
        for (int t = 0; t < KS; ++t) a = fmaf(wr[t], wincol[k + t], a);
        acc[k] = clip01(a);
      }
      chain_and_store<USE_LISTS>(acc, P, b, gx, gy0, np, rain_u, nlist, packed, op);
    }
  } else {
    // ---- no blur: pure streaming path (no LDS, no sync) ----
    for (int i = tid; i < 512; i += 256) {
      int xq = i & 63, sy = i >> 6;
      int gx = tx0 + xq, gy0 = ty0 + sy * 8;
      float acc[8];
      #pragma unroll
      for (int k = 0; k < 8; ++k) acc[k] = xp[(size_t)(gy0 + k) * NW + gx];
      chain_and_store<USE_LISTS>(acc, P, b, gx, gy0, np, rain_u, nlist, packed, op);
    }
  }
}

extern "C" void kernel_launch(void* const* d_in, const int* in_sizes, int n_in,
                              void* d_out, int out_size, void* d_ws, size_t ws_size,
                              hipStream_t stream)
{
  const float* x            = (const float*)d_in[0];
  const float* sigma_u      = (const float*)d_in[1];
  const float* glare_u      = (const float*)d_in[2];
  const float* occ_u        = (const float*)d_in[3];
  const float* rain_u       = (const float*)d_in[4];
  const float* rain_n_u     = (const float*)d_in[5];
  const float* rain_alpha_u = (const float*)d_in[6];
  const float* noise_u      = (const float*)d_in[7];
  const float* noise_amt_u  = (const float*)d_in[8];
  const int*   flags        = (const int*)d_in[9];
  float* out = (float*)d_out;

  const size_t nlist_bytes  = (size_t)NB * NW * sizeof(int);
  const size_t packed_bytes = (size_t)NB * NW * NS * sizeof(unsigned);
  const bool use_lists = ws_size >= nlist_bytes + packed_bytes;

  int* nlist = (int*)d_ws;
  unsigned* packed = (unsigned*)((char*)d_ws + nlist_bytes);

  dim3 grid(64, NC, NB);   // 8x8 tiles, 3 channels, 32 samples
  if (use_lists) {
    rain_cols_kernel<<<(NB * NW + 255) / 256, 256, 0, stream>>>(rain_u, rain_n_u, nlist, packed);
    fused_kernel<true><<<grid, 256, 0, stream>>>(
        x, sigma_u, glare_u, occ_u, rain_u, rain_n_u, rain_alpha_u,
        noise_u, noise_amt_u, flags, nlist, packed, out);
  } else {
    fused_kernel<false><<<grid, 256, 0, stream>>>(
        x, sigma_u, glare_u, occ_u, rain_u, rain_n_u, rain_alpha_u,
        noise_u, noise_amt_u, flags, (const int*)nullptr, (const unsigned*)nullptr, out);
  }
}

// Round 3
// 130.810 us; speedup vs baseline: 1.5114x; 1.5114x over previous
//
#include <hip/hip_runtime.h>

#define NB   32
#define NC   3
#define NH   512
#define NW   512
#define KS   25
#define HALF 12
#define TILE 64
#define HALO 88    // TILE + 2*HALF
#define NS   60

__device__ __forceinline__ float clip01(float v) { return fminf(fmaxf(v, 0.f), 1.f); }

struct PParams {
  int f1, f2, f3, f4;
  float intensity, cx, cy, rxi, ryi;
  float oy0, oy1, ox0, ox1;
  float log1ma, nrain;
  float thr_lo, thr_hi;
};

// ---- rain column lists: each streak covers exactly 2 columns ----
__global__ void rain_cols_kernel(const float* __restrict__ rain_u,
                                 const float* __restrict__ rain_n_u,
                                 int* __restrict__ nlist,
                                 unsigned* __restrict__ packed)
{
  int t = blockIdx.x * 256 + threadIdx.x;      // t in [0, 32*512)
  if (t >= NB * NW) return;
  int b = t >> 9, wcol = t & 511;
  float n = floorf(20.f + 41.f * rain_n_u[b]);
  float wf = (float)wcol;
  int cnt = 0;
  for (int s = 0; s < NS; ++s) {
    if ((float)s < n) {
      float xc = floorf(rain_u[(b * NS + s) * 3 + 0] * 512.f);
      if (wf >= xc - 1.f && wf <= xc) {
        float y0 = floorf(rain_u[(b * NS + s) * 3 + 1] * 256.f);
        float y1 = 256.f + floorf(rain_u[(b * NS + s) * 3 + 2] * 256.f);
        packed[t * NS + cnt] = (((unsigned)y0) << 16) | (unsigned)y1;
        ++cnt;
      }
    }
  }
  nlist[t] = cnt;
}

// ---- pointwise chain applied to an 8-row column strip ----
template<bool USE_LISTS>
__device__ __forceinline__ void chain_and_store(
    float acc[8], const PParams& P, int b, int gx, int gy0,
    const float* __restrict__ noise_plane, const float* __restrict__ rain_u,
    const int* __restrict__ nlist, const unsigned* __restrict__ packed,
    float* __restrict__ out_plane)
{
  const float fx = (float)gx;

  // 2. glare
  if (P.f1) {
    float dx = (fx - P.cx) * P.rxi;
    float dx2 = dx * dx;
    #pragma unroll
    for (int k = 0; k < 8; ++k) {
      float dy = ((float)(gy0 + k) - P.cy) * P.ryi;
      float g = __expf(-(dx2 + dy * dy));
      acc[k] = clip01(acc[k] + P.intensity * g);
    }
  }
  // 3. occlusion
  if (P.f2 && fx >= P.ox0 && fx < P.ox1) {
    #pragma unroll
    for (int k = 0; k < 8; ++k) {
      float fy = (float)(gy0 + k);
      if (fy >= P.oy0 && fy < P.oy1) acc[k] = 0.f;
    }
  }
  // 4. rain
  if (P.f3) {
    float cnt[8];
    #pragma unroll
    for (int k = 0; k < 8; ++k) cnt[k] = 0.f;
    if (USE_LISTS) {
      int base = b * NW + gx;
      int c = nlist[base];
      for (int j = 0; j < c; ++j) {
        unsigned p = packed[base * NS + j];
        float y0 = (float)(p >> 16), y1 = (float)(p & 0xffffu);
        #pragma unroll
        for (int k = 0; k < 8; ++k) {
          float fy = (float)(gy0 + k);
          cnt[k] += (fy >= y0 && fy < y1) ? 1.f : 0.f;
        }
      }
    } else {
      for (int s = 0; s < NS; ++s) {
        if ((float)s < P.nrain) {
          float xc = floorf(rain_u[(b * NS + s) * 3 + 0] * 512.f);
          if (fx >= xc - 1.f && fx <= xc) {
            float y0 = floorf(rain_u[(b * NS + s) * 3 + 1] * 256.f);
            float y1 = 256.f + floorf(rain_u[(b * NS + s) * 3 + 2] * 256.f);
            #pragma unroll
            for (int k = 0; k < 8; ++k) {
              float fy = (float)(gy0 + k);
              cnt[k] += (fy >= y0 && fy < y1) ? 1.f : 0.f;
            }
          }
        }
      }
    }
    #pragma unroll
    for (int k = 0; k < 8; ++k) {
      if (cnt[k] != 0.f) {
        float d = exp2f(cnt[k] * P.log1ma);
        acc[k] = clip01(acc[k] * d + (1.f - d));
      }
    }
  }
  // 5. salt & pepper (read noise only when gated on)
  if (P.f4) {
    const float* np = noise_plane + (size_t)gy0 * NW + gx;
    #pragma unroll
    for (int k = 0; k < 8; ++k) {
      float nv = np[(size_t)k * NW];
      acc[k] = (nv < P.thr_lo) ? 0.f : ((nv > P.thr_hi) ? 1.f : acc[k]);
    }
  }
  float* op = out_plane + (size_t)gy0 * NW + gx;
  #pragma unroll
  for (int k = 0; k < 8; ++k) op[(size_t)k * NW] = acc[k];
}

// __launch_bounds__(256, 4): VGPR budget ~128 — this kernel needs ~75 live
// registers (win[28]+wr[25]+acc). (256,6) capped the budget at ~85 and the
// allocator spilled to scratch (VGPR=40, WRITE_SIZE doubled, occupancy 39%).
template<bool USE_LISTS>
__global__ __launch_bounds__(256, 4)
void fused_kernel(const float* __restrict__ x, const float* __restrict__ sigma_u,
                  const float* __restrict__ glare_u, const float* __restrict__ occ_u,
                  const float* __restrict__ rain_u, const float* __restrict__ rain_n_u,
                  const float* __restrict__ rain_alpha_u, const float* __restrict__ noise_u,
                  const float* __restrict__ noise_amt_u, const int* __restrict__ flags,
                  const int* __restrict__ nlist, const unsigned* __restrict__ packed,
                  float* __restrict__ out)
{
  const int b = blockIdx.z, ch = blockIdx.y;
  const int ty0 = (blockIdx.x >> 3) * TILE, tx0 = (blockIdx.x & 7) * TILE;
  const int tid = threadIdx.x;

  const int f0 = flags[b * 5 + 0] > 0;
  PParams P;
  P.f1 = flags[b * 5 + 1] > 0;
  P.f2 = flags[b * 5 + 2] > 0;
  P.f3 = flags[b * 5 + 3] > 0;
  P.f4 = flags[b * 5 + 4] > 0;
  {
    float g0 = glare_u[b * 5 + 0], g1 = glare_u[b * 5 + 1], g2 = glare_u[b * 5 + 2],
          g3 = glare_u[b * 5 + 3], g4 = glare_u[b * 5 + 4];
    P.intensity = 0.4f + 0.5f * g0;
    P.rxi = 1.f / ((0.1f + 0.25f * g1) * 256.f);   // W/2
    P.ryi = 1.f / ((0.1f + 0.25f * g2) * 256.f);   // H/2
    P.cx = (0.2f + 0.6f * g3) * 512.f;
    P.cy = (0.2f + 0.6f * g4) * 512.f;
    float o0 = occ_u[b * 4 + 0], o1 = occ_u[b * 4 + 1],
          o2 = occ_u[b * 4 + 2], o3 = occ_u[b * 4 + 3];
    float ph = floorf(512.f * (0.1f + 0.3f * o0));
    float pw = floorf(512.f * (0.1f + 0.3f * o1));
    P.oy0 = floorf(o2 * (512.f - ph)); P.oy1 = P.oy0 + ph;
    P.ox0 = floorf(o3 * (512.f - pw)); P.ox1 = P.ox0 + pw;
    P.log1ma = log2f(1.f - (0.15f + 0.35f * rain_alpha_u[b]));
    P.nrain = floorf(20.f + 41.f * rain_n_u[b]);
    float half_amt = 0.5f * (0.01f + 0.07f * noise_amt_u[b]);
    P.thr_lo = half_amt; P.thr_hi = 1.f - half_amt;
  }

  const size_t plane = ((size_t)(b * NC + ch)) * (size_t)(NH * NW);
  const float* xp = x + plane;
  const float* np = noise_u + plane;
  float* op = out + plane;

  // Only the H-blurred tile is staged in LDS: 88 rows x 64 cols = 22.5 KB
  __shared__ __align__(16) float s_hb[HALO * TILE];

  if (f0) {
    // ---- blur weights in registers (25 expf per thread, no LDS, no sync) ----
    float sig = 1.f + 3.f * sigma_u[b];
    float ninv2s2 = -1.f / (2.f * sig * sig);
    float wr[KS]; float s = 0.f;
    #pragma unroll
    for (int t = 0; t < KS; ++t) {
      float d = (float)t - 12.f;
      wr[t] = expf(d * d * ninv2s2);
      s += wr[t];
    }
    float inv = 1.f / s;
    #pragma unroll
    for (int t = 0; t < KS; ++t) wr[t] *= inv;

    // ---- stage 1: horizontal blur straight from global (L1/L2-cached rows),
    //      4 outputs/thread, aligned float4 loads on the interior fast path ----
    for (int i = tid; i < HALO * 16; i += 256) {
      int r = i >> 4, q = i & 15;
      int gy = ty0 + r - HALF;
      float a0 = 0.f, a1 = 0.f, a2 = 0.f, a3 = 0.f;
      if ((unsigned)gy < (unsigned)NH) {
        const float* rowp = xp + (size_t)gy * NW;
        int gx0 = tx0 + q * 4;                    // first of 4 output columns
        float win[28];
        if (gx0 - HALF >= 0 && gx0 + 15 < NW) {   // interior: 7 aligned float4
          #pragma unroll
          for (int j = 0; j < 7; ++j) {
            float4 v = *reinterpret_cast<const float4*>(rowp + gx0 - HALF + 4 * j);
            win[4 * j + 0] = v.x; win[4 * j + 1] = v.y;
            win[4 * j + 2] = v.z; win[4 * j + 3] = v.w;
          }
        } else {                                  // x-edge: guarded scalar loads
          #pragma unroll
          for (int j = 0; j < 28; ++j) {
            int gx = gx0 - HALF + j;
            win[j] = ((unsigned)gx < (unsigned)NW) ? rowp[gx] : 0.f;
          }
        }
        #pragma unroll
        for (int t = 0; t < KS; ++t) {
          float wt = wr[t];
          a0 = fmaf(wt, win[t + 0], a0);
          a1 = fmaf(wt, win[t + 1], a1);
          a2 = fmaf(wt, win[t + 2], a2);
          a3 = fmaf(wt, win[t + 3], a3);
        }
      }
      *reinterpret_cast<float4*>(&s_hb[r * TILE + (i & 15) * 4]) =
          make_float4(a0, a1, a2, a3);
    }
    __syncthreads();

    // ---- stage 2: vertical blur on 8-row strips + fused pointwise chain ----
    for (int i = tid; i < 512; i += 256) {
      int xq = i & 63, sy = i >> 6;
      int gx = tx0 + xq, gy0 = ty0 + sy * 8;
      float wincol[32];
      #pragma unroll
      for (int j = 0; j < 32; ++j) wincol[j] = s_hb[(sy * 8 + j) * TILE + xq];
      float acc[8];
      #pragma unroll
      for (int k = 0; k < 8; ++k) {
        float a = 0.f;
        #pragma unroll
        for (int t = 0; t < KS; ++t) a = fmaf(wr[t], wincol[k + t], a);
        acc[k] = clip01(a);
      }
      chain_and_store<USE_LISTS>(acc, P, b, gx, gy0, np, rain_u, nlist, packed, op);
    }
  } else {
    // ---- no blur: pure streaming path (no LDS, no sync) ----
    for (int i = tid; i < 512; i += 256) {
      int xq = i & 63, sy = i >> 6;
      int gx = tx0 + xq, gy0 = ty0 + sy * 8;
      float acc[8];
      #pragma unroll
      for (int k = 0; k < 8; ++k) acc[k] = xp[(size_t)(gy0 + k) * NW + gx];
      chain_and_store<USE_LISTS>(acc, P, b, gx, gy0, np, rain_u, nlist, packed, op);
    }
  }
}

extern "C" void kernel_launch(void* const* d_in, const int* in_sizes, int n_in,
                              void* d_out, int out_size, void* d_ws, size_t ws_size,
                              hipStream_t stream)
{
  const float* x            = (const float*)d_in[0];
  const float* sigma_u      = (const float*)d_in[1];
  const float* glare_u      = (const float*)d_in[2];
  const float* occ_u        = (const float*)d_in[3];
  const float* rain_u       = (const float*)d_in[4];
  const float* rain_n_u     = (const float*)d_in[5];
  const float* rain_alpha_u = (const float*)d_in[6];
  const float* noise_u      = (const float*)d_in[7];
  const float* noise_amt_u  = (const float*)d_in[8];
  const int*   flags        = (const int*)d_in[9];
  float* out = (float*)d_out;

  const size_t nlist_bytes  = (size_t)NB * NW * sizeof(int);
  const size_t packed_bytes = (size_t)NB * NW * NS * sizeof(unsigned);
  const bool use_lists = ws_size >= nlist_bytes + packed_bytes;

  int* nlist = (int*)d_ws;
  unsigned* packed = (unsigned*)((char*)d_ws + nlist_bytes);

  dim3 grid(64, NC, NB);   // 8x8 tiles, 3 channels, 32 samples
  if (use_lists) {
    rain_cols_kernel<<<(NB * NW + 255) / 256, 256, 0, stream>>>(rain_u, rain_n_u, nlist, packed);
    fused_kernel<true><<<grid, 256, 0, stream>>>(
        x, sigma_u, glare_u, occ_u, rain_u, rain_n_u, rain_alpha_u,
        noise_u, noise_amt_u, flags, nlist, packed, out);
  } else {
    fused_kernel<false><<<grid, 256, 0, stream>>>(
        x, sigma_u, glare_u, occ_u, rain_u, rain_n_u, rain_alpha_u,
        noise_u, noise_amt_u, flags, (const int*)nullptr, (const unsigned*)nullptr, out);
  }
}